// Round 12
// baseline (402.764 us; speedup 1.0000x reference)
//
#include <hip/hip_runtime.h>
#include <hip/hip_bf16.h>

#define IN_F 128
#define HF 256
#define BN_EPS 1e-5f
#define SELU_SCALE 1.0507009873554805f
#define SELU_ALPHA 1.6732632423543772f

typedef __attribute__((ext_vector_type(8))) _Float16 half8;
typedef __attribute__((ext_vector_type(2))) unsigned int u32x2;
typedef __attribute__((ext_vector_type(4))) float f32x4;

__device__ __forceinline__ short f2h(float f) {
    _Float16 h = (_Float16)f;               // RTNE fp32->fp16
    return __builtin_bit_cast(short, h);
}

// fast SELU: native v_exp_f32
__device__ __forceinline__ float selu_f(float x) {
    const float SA = SELU_SCALE * SELU_ALPHA;
    float e = __expf(x);
    return x > 0.f ? SELU_SCALE * x : SA * e - SA;
}

// pack 2 fp32 -> 2 fp16 (RTZ), one instruction
__device__ __forceinline__ unsigned int pk2h(float a, float b) {
    return __builtin_bit_cast(unsigned int, __builtin_amdgcn_cvt_pkrtz(a, b));
}

// async global->LDS, 16B/lane; LDS dest MUST be wave-uniform (lane*16 implicit)
__device__ __forceinline__ void gld_lds16(const void* g, void* l) {
    __builtin_amdgcn_global_load_lds(
        (const __attribute__((address_space(1))) unsigned int*)g,
        (__attribute__((address_space(3))) unsigned int*)l, 16, 0, 0);
}

// Fold BN into weights. Layout = fused kernel's per-step (BK=32) B staging:
// Wf[layer][kk(8)][kc(4)][n(256)][j(8)] fp16, k = kk*32 + kc*8 + j.
// Each (layer,kk) chunk is 16KB contiguous.
__global__ void prep_kernel(const float* __restrict__ W0, const float* __restrict__ b0,
                            const float* __restrict__ g0, const float* __restrict__ beta0,
                            const float* __restrict__ m0, const float* __restrict__ v0,
                            const float* __restrict__ Ws, const float* __restrict__ bs,
                            const float* __restrict__ gs, const float* __restrict__ betas,
                            const float* __restrict__ ms, const float* __restrict__ vs,
                            unsigned short* __restrict__ Wf, float* __restrict__ biasArr) {
    int b = blockIdx.x;
    int layer = b >> 8;
    int n = b & 255;
    int k = threadIdx.x;
    const float *W, *bb, *g, *be, *m, *v;
    if (layer == 0) { W = W0; bb = b0; g = g0; be = beta0; m = m0; v = v0; }
    else {
        int i = layer - 1;
        W = Ws + (size_t)i * HF * HF; bb = bs + i * HF; g = gs + i * HF;
        be = betas + i * HF; m = ms + i * HF; v = vs + i * HF;
    }
    float s = g[n] * rsqrtf(v[n] + BN_EPS);
    int kk = k >> 5, kc = (k >> 3) & 3, j = k & 7;
    Wf[((((size_t)layer * 8 + kk) * 4 + kc) * 256 + n) * 8 + j] =
        (unsigned short)f2h(W[n * HF + k] * s);
    if (k == 0) biasArr[layer * HF + n] = (bb[n] - m[n]) * s + be[n];
}

__global__ void count_kernel(const int* __restrict__ dstI, int* __restrict__ cnt, int E) {
    int i = blockIdx.x * 256 + threadIdx.x;
    if (i < E) atomicAdd(cnt + dstI[i], 1);
}

__global__ void finalize_kernel(float* __restrict__ agg, const int* __restrict__ cnt) {
    int n = blockIdx.x;
    float c = fmaxf((float)cnt[n], 1.f);
    agg[(size_t)n * HF + threadIdx.x] = agg[(size_t)n * HF + threadIdx.x] / c;
}

// Fused 3-layer edge MLP. Block = 64 edges x all 256 cols; 256 thr = 4 waves,
// each wave 64 rows x 64 cols (4x4 frags of mfma_f32_16x16x32_f16).
// A_act: 64 rows x 512B fp16 @0, XOR-swizzled (byte ^ ((row&7)<<4)), resident
//   across layers. B: DOUBLE-buffered 2x16KB @32768 (BK=32). Steady-state
//   step: {issue stageB(next->other buf); frag reads (cur); 16 MFMA; barrier}.
//   Reads and MFMAs share one barrier region -> compiler overlaps them; the
//   stage has the whole step to land. ONE barrier per step (8/layer).
// Layers 1-2 swapped mfma operands (lane&15=edge, reg-dim=col) -> handoff =
//   cvt_pkrtz + b64 swizzled writes. Layer 3 unswapped -> coalesced atomics.
__global__ __launch_bounds__(256, 2)
void fused_kernel(const float* __restrict__ x,
                  const int* __restrict__ dstI, const int* __restrict__ srcI,
                  const unsigned char* __restrict__ Wfb,
                  const float* __restrict__ biasArr,
                  unsigned char* __restrict__ hB, float* __restrict__ agg) {
    __shared__ __align__(16) unsigned char lds[65536];

    const int base = blockIdx.x * 64;
    const int t = threadIdx.x;
    const int lane = t & 63;
    const int w = t >> 6;           // 0..3 : 64-col slab
    const int lrow = lane & 15;
    const int lgrp = lane >> 4;

    // stage B(L,kk) -> buffer buf: 16KB, 4 wave-uniform gld_lds rounds
    auto stageB = [&](int L, int kk, int buf) {
        const unsigned char* src = Wfb + ((size_t)(L * 8 + kk) << 14);
        unsigned char* dstBase = lds + 32768 + buf * 16384 + w * 1024;
#pragma unroll
        for (int i = 0; i < 4; ++i)
            gld_lds16(src + (i * 256 + t) * 16, dstBase + i * 4096);
    };

    stageB(0, 0, 0);   // prologue stage overlaps the gather below

    // ---- layer-1 A fill: gather x fp32 (L2/L3-hot), pack, swizzled write ----
    {
        int r = t >> 2, q = t & 3;                 // row, col-quarter
        int idx = (q < 2 ? dstI : srcI)[base + r];
        const float* xr = x + (size_t)idx * IN_F + (q & 1) * 64;
        int swz = (r & 7) << 4;
#pragma unroll
        for (int u = 0; u < 16; ++u) {
            f32x4 v = *(const f32x4*)(xr + u * 4);
            u32x2 hv = {pk2h(v[0], v[1]), pk2h(v[2], v[3])};
            *(u32x2*)&lds[r * 512 + ((q * 128 + u * 8) ^ swz)] = hv;
        }
    }
    __syncthreads();   // stage(0,0) landed + A_act visible

    f32x4 acc[4][4];
    const f32x4 zero = {0.f, 0.f, 0.f, 0.f};

#pragma unroll
    for (int L = 0; L < 3; ++L) {
#pragma unroll
        for (int mi = 0; mi < 4; ++mi)
#pragma unroll
            for (int ni = 0; ni < 4; ++ni) acc[mi][ni] = zero;

#pragma unroll
        for (int kk = 0; kk < 8; ++kk) {
            const int p = (L * 8 + kk) & 1;
            // issue next stage first (T14 issue-early): lands by end-of-step barrier
            if (kk < 7) stageB(L, kk + 1, p ^ 1);
            else if (L < 2) stageB(L + 1, 0, p ^ 1);

            const unsigned char* Bb = lds + 32768 + p * 16384;
            half8 af[4], bf[4];
#pragma unroll
            for (int mi = 0; mi < 4; ++mi) {
                int row = mi * 16 + lrow;
                af[mi] = *(const half8*)&lds[row * 512 +
                    ((kk * 64 + lgrp * 16) ^ ((row & 7) << 4))];
            }
#pragma unroll
            for (int ni = 0; ni < 4; ++ni)
                bf[ni] = *(const half8*)&Bb[lgrp * 4096 + (w * 64 + ni * 16 + lrow) * 16];

            if (L < 2) {
#pragma unroll
                for (int mi = 0; mi < 4; ++mi)
#pragma unroll
                    for (int ni = 0; ni < 4; ++ni)
                        acc[mi][ni] = __builtin_amdgcn_mfma_f32_16x16x32_f16(
                            bf[ni], af[mi], acc[mi][ni], 0, 0, 0);
            } else {
#pragma unroll
                for (int mi = 0; mi < 4; ++mi)
#pragma unroll
                    for (int ni = 0; ni < 4; ++ni)
                        acc[mi][ni] = __builtin_amdgcn_mfma_f32_16x16x32_f16(
                            af[mi], bf[ni], acc[mi][ni], 0, 0, 0);
            }
            __syncthreads();   // reads of Bb/A_act done; stage->p^1 drained
        }

        if (L < 2) {
            // ---- handoff (swapped layout): lane&15=edge, reg-dim=col ----
#pragma unroll
            for (int ni = 0; ni < 4; ++ni) {
                f32x4 bv = *(const f32x4*)(biasArr + L * HF + w * 64 + ni * 16 + lgrp * 4);
#pragma unroll
                for (int mi = 0; mi < 4; ++mi) {
                    int row = mi * 16 + lrow;
                    float v0 = selu_f(acc[mi][ni][0] + bv[0]);
                    float v1 = selu_f(acc[mi][ni][1] + bv[1]);
                    float v2 = selu_f(acc[mi][ni][2] + bv[2]);
                    float v3 = selu_f(acc[mi][ni][3] + bv[3]);
                    u32x2 d = {pk2h(v0, v1), pk2h(v2, v3)};
                    *(u32x2*)&lds[row * 512 +
                        ((w * 128 + ni * 32 + lgrp * 8) ^ ((row & 7) << 4))] = d;
                }
            }
            __syncthreads();   // A_act(L+1) visible before next layer's reads
        } else {
            // ---- epilogue (unswapped): coalesced atomics + full-line h ----
            float bc[4];
#pragma unroll
            for (int ni = 0; ni < 4; ++ni) bc[ni] = biasArr[2 * HF + w * 64 + ni * 16 + lrow];
            unsigned char* EP = lds + 32768;
#pragma unroll
            for (int cc = 0; cc < 2; ++cc) {
                if (cc) __syncthreads();
#pragma unroll
                for (int m2 = 0; m2 < 2; ++m2) {
                    int mi = cc * 2 + m2;
#pragma unroll
                    for (int ni = 0; ni < 4; ++ni)
#pragma unroll
                        for (int r = 0; r < 4; ++r) {
                            int lr = m2 * 16 + lgrp * 4 + r;       // 0..31
                            int cg = w * 64 + ni * 16 + lrow;
                            float val = selu_f(acc[mi][ni][r] + bc[ni]);
                            *(float*)&EP[lr * 1024 + ((cg * 4) ^ ((lr & 7) << 4))] = val;
                            int e = base + cc * 32 + lr;
                            atomicAdd(agg + (size_t)dstI[e] * HF + cg, val);
                        }
                }
                __syncthreads();
#pragma unroll
                for (int i = 0; i < 8; ++i) {
                    int f = t + i * 256;                  // 2048 x 16B = 32 rows x 64
                    int row = f >> 6, ch = f & 63;
                    f32x4 v = *(const f32x4*)&EP[row * 1024 + ((ch * 16) ^ ((row & 7) << 4))];
                    *(f32x4*)(hB + (size_t)(base + cc * 32 + row) * 1024 + ch * 16) = v;
                }
            }
        }
    }
}

extern "C" void kernel_launch(void* const* d_in, const int* in_sizes, int n_in,
                              void* d_out, int out_size, void* d_ws, size_t ws_size,
                              hipStream_t stream) {
    const float* x     = (const float*)d_in[0];
    const int*   ei    = (const int*)d_in[1];
    const float* W0    = (const float*)d_in[2];
    const float* b0    = (const float*)d_in[3];
    const float* g0    = (const float*)d_in[4];
    const float* beta0 = (const float*)d_in[5];
    const float* m0    = (const float*)d_in[6];
    const float* v0    = (const float*)d_in[7];
    const float* Ws    = (const float*)d_in[8];
    const float* bs    = (const float*)d_in[9];
    const float* gs    = (const float*)d_in[10];
    const float* betas = (const float*)d_in[11];
    const float* ms    = (const float*)d_in[12];
    const float* vs    = (const float*)d_in[13];

    const int Nn = in_sizes[0] / IN_F;   // 20000
    const int E  = in_sizes[1] / 2;      // 320000

    float* agg  = (float*)d_out;
    float* hptr = agg + (size_t)Nn * HF;   // final h region of d_out

    // ws: Wf (384KB fp16, staged layout) | biasArr (3KB) | cnt (80KB)
    unsigned short* Wf = (unsigned short*)d_ws;
    float* biasArr = (float*)((char*)d_ws + 3 * HF * HF * sizeof(unsigned short));
    int* cnt = (int*)((char*)d_ws + 3 * HF * HF * sizeof(unsigned short) + 3 * HF * sizeof(float));

    const int* srcI = ei;        // edge_index[0]
    const int* dstI = ei + E;    // edge_index[1]

    prep_kernel<<<3 * HF, HF, 0, stream>>>(W0, b0, g0, beta0, m0, v0,
                                           Ws, bs, gs, betas, ms, vs, Wf, biasArr);
    hipMemsetAsync(cnt, 0, (size_t)Nn * sizeof(int), stream);
    hipMemsetAsync(agg, 0, (size_t)Nn * HF * sizeof(float), stream);
    count_kernel<<<(E + 255) / 256, 256, 0, stream>>>(dstI, cnt, E);

    fused_kernel<<<E / 64, 256, 0, stream>>>(x, dstI, srcI,
                                             (const unsigned char*)Wf, biasArr,
                                             (unsigned char*)hptr, agg);

    finalize_kernel<<<Nn, HF, 0, stream>>>(agg, cnt);
}

// Round 13
// 394.147 us; speedup vs baseline: 1.0219x; 1.0219x over previous
//
#include <hip/hip_runtime.h>
#include <hip/hip_bf16.h>

#define IN_F 128
#define HF 256
#define BN_EPS 1e-5f
#define SELU_SCALE 1.0507009873554805f
#define SELU_ALPHA 1.6732632423543772f

typedef __attribute__((ext_vector_type(8))) _Float16 half8;
typedef __attribute__((ext_vector_type(2))) unsigned int u32x2;
typedef __attribute__((ext_vector_type(4))) float f32x4;

__device__ __forceinline__ short f2h(float f) {
    _Float16 h = (_Float16)f;               // RTNE fp32->fp16
    return __builtin_bit_cast(short, h);
}

// fast SELU: native v_exp_f32
__device__ __forceinline__ float selu_f(float x) {
    const float SA = SELU_SCALE * SELU_ALPHA;
    float e = __expf(x);
    return x > 0.f ? SELU_SCALE * x : SA * e - SA;
}

// pack 2 fp32 -> 2 fp16 (RTZ), one instruction
__device__ __forceinline__ unsigned int pk2h(float a, float b) {
    return __builtin_bit_cast(unsigned int, __builtin_amdgcn_cvt_pkrtz(a, b));
}

// async global->LDS, 16B/lane; LDS dest MUST be wave-uniform (lane*16 implicit)
__device__ __forceinline__ void gld_lds16(const void* g, void* l) {
    __builtin_amdgcn_global_load_lds(
        (const __attribute__((address_space(1))) unsigned int*)g,
        (__attribute__((address_space(3))) unsigned int*)l, 16, 0, 0);
}

// Fold BN into weights. Layout = fused kernel's per-step (BK=32) B staging:
// Wf[layer][kk(8)][kc(4)][n(256)][j(8)] fp16, k = kk*32 + kc*8 + j.
// Each (layer,kk) chunk is 16KB contiguous.
__global__ void prep_kernel(const float* __restrict__ W0, const float* __restrict__ b0,
                            const float* __restrict__ g0, const float* __restrict__ beta0,
                            const float* __restrict__ m0, const float* __restrict__ v0,
                            const float* __restrict__ Ws, const float* __restrict__ bs,
                            const float* __restrict__ gs, const float* __restrict__ betas,
                            const float* __restrict__ ms, const float* __restrict__ vs,
                            unsigned short* __restrict__ Wf, float* __restrict__ biasArr) {
    int b = blockIdx.x;
    int layer = b >> 8;
    int n = b & 255;
    int k = threadIdx.x;
    const float *W, *bb, *g, *be, *m, *v;
    if (layer == 0) { W = W0; bb = b0; g = g0; be = beta0; m = m0; v = v0; }
    else {
        int i = layer - 1;
        W = Ws + (size_t)i * HF * HF; bb = bs + i * HF; g = gs + i * HF;
        be = betas + i * HF; m = ms + i * HF; v = vs + i * HF;
    }
    float s = g[n] * rsqrtf(v[n] + BN_EPS);
    int kk = k >> 5, kc = (k >> 3) & 3, j = k & 7;
    Wf[((((size_t)layer * 8 + kk) * 4 + kc) * 256 + n) * 8 + j] =
        (unsigned short)f2h(W[n * HF + k] * s);
    if (k == 0) biasArr[layer * HF + n] = (bb[n] - m[n]) * s + be[n];
}

__global__ void count_kernel(const int* __restrict__ dstI, int* __restrict__ cnt, int E) {
    int i = blockIdx.x * 256 + threadIdx.x;
    if (i < E) atomicAdd(cnt + dstI[i], 1);
}

__global__ void finalize_kernel(float* __restrict__ agg, const int* __restrict__ cnt) {
    int n = blockIdx.x;
    float c = fmaxf((float)cnt[n], 1.f);
    agg[(size_t)n * HF + threadIdx.x] = agg[(size_t)n * HF + threadIdx.x] / c;
}

// Fused 3-layer edge MLP. Block = 64 edges x all 256 cols; 256 thr = 4 waves;
// each wave ALL 64 rows x its 64-col slab (4x4 frags of mfma_f32_16x16x32_f16).
// LDS 48KB -> 3 blocks/CU (12 waves): A_act 32KB @0 (64 rows x 512B fp16,
// XOR-swizzled byte^((row&7)<<4), resident across layers); B single 16KB
// @32768 (BK=32, [kc(4)][n(256)][16B]). K-step: {barrier; frag reads; barrier;
// stageB(next) under 16 MFMA}. Layers 1-2 swapped operands (lane&15=edge,
// reg-dim=col) -> pkrtz+b64 handoff; layer 3 unswapped -> coalesced atomics.
// Epilogue: 4 rounds of 16 rows (mi=cc) through the 16KB B region.
__global__ __launch_bounds__(256, 3)
void fused_kernel(const float* __restrict__ x,
                  const int* __restrict__ dstI, const int* __restrict__ srcI,
                  const unsigned char* __restrict__ Wfb,
                  const float* __restrict__ biasArr,
                  unsigned char* __restrict__ hB, float* __restrict__ agg) {
    __shared__ __align__(16) unsigned char lds[49152];

    const int base = blockIdx.x * 64;
    const int t = threadIdx.x;
    const int lane = t & 63;
    const int w = t >> 6;           // 0..3 : 64-col slab
    const int lrow = lane & 15;
    const int lgrp = lane >> 4;

    // stage B(L,kk): 16KB, 4 wave-uniform gld_lds rounds
    auto stageB = [&](int L, int kk) {
        const unsigned char* src = Wfb + ((size_t)(L * 8 + kk) << 14);
        unsigned char* dstBase = lds + 32768 + w * 1024;
#pragma unroll
        for (int i = 0; i < 4; ++i)
            gld_lds16(src + (i * 256 + t) * 16, dstBase + i * 4096);
    };

    stageB(0, 0);   // prologue stage overlaps the gather below

    // ---- layer-1 A fill: gather x fp32 (L2/L3-hot), pack, swizzled write ----
    {
        int r = t >> 2, q = t & 3;                 // row, col-quarter
        int idx = (q < 2 ? dstI : srcI)[base + r];
        const float* xr = x + (size_t)idx * IN_F + (q & 1) * 64;
        int swz = (r & 7) << 4;
#pragma unroll
        for (int u = 0; u < 16; ++u) {
            f32x4 v = *(const f32x4*)(xr + u * 4);
            u32x2 hv = {pk2h(v[0], v[1]), pk2h(v[2], v[3])};
            *(u32x2*)&lds[r * 512 + ((q * 128 + u * 8) ^ swz)] = hv;
        }
    }

    f32x4 acc[4][4];
    const f32x4 zero = {0.f, 0.f, 0.f, 0.f};

#pragma unroll
    for (int L = 0; L < 3; ++L) {
#pragma unroll
        for (int mi = 0; mi < 4; ++mi)
#pragma unroll
            for (int ni = 0; ni < 4; ++ni) acc[mi][ni] = zero;

#pragma unroll
        for (int kk = 0; kk < 8; ++kk) {
            __syncthreads();   // B(kk) staged; A_act (gather/handoff) visible

            half8 af[4], bf[4];
#pragma unroll
            for (int mi = 0; mi < 4; ++mi) {
                int row = mi * 16 + lrow;
                af[mi] = *(const half8*)&lds[row * 512 +
                    ((kk * 64 + lgrp * 16) ^ ((row & 7) << 4))];
            }
#pragma unroll
            for (int ni = 0; ni < 4; ++ni)
                bf[ni] = *(const half8*)&lds[32768 + lgrp * 4096 +
                                             (w * 64 + ni * 16 + lrow) * 16];
            __syncthreads();   // all reads done -> B buffer free

            // stage next B under the MFMA cluster (lands by next loop-top barrier)
            if (kk < 7) stageB(L, kk + 1);
            else if (L < 2) stageB(L + 1, 0);

            if (L < 2) {
#pragma unroll
                for (int mi = 0; mi < 4; ++mi)
#pragma unroll
                    for (int ni = 0; ni < 4; ++ni)
                        acc[mi][ni] = __builtin_amdgcn_mfma_f32_16x16x32_f16(
                            bf[ni], af[mi], acc[mi][ni], 0, 0, 0);
            } else {
#pragma unroll
                for (int mi = 0; mi < 4; ++mi)
#pragma unroll
                    for (int ni = 0; ni < 4; ++ni)
                        acc[mi][ni] = __builtin_amdgcn_mfma_f32_16x16x32_f16(
                            af[mi], bf[ni], acc[mi][ni], 0, 0, 0);
            }
        }

        if (L < 2) {
            // ---- handoff (swapped layout): lane&15=edge, reg-dim=col ----
            // A_act reads finished at last step's second barrier; rewrite now,
            // published by next layer's loop-top barrier.
#pragma unroll
            for (int ni = 0; ni < 4; ++ni) {
                f32x4 bv = *(const f32x4*)(biasArr + L * HF + w * 64 + ni * 16 + lgrp * 4);
#pragma unroll
                for (int mi = 0; mi < 4; ++mi) {
                    int row = mi * 16 + lrow;
                    float v0 = selu_f(acc[mi][ni][0] + bv[0]);
                    float v1 = selu_f(acc[mi][ni][1] + bv[1]);
                    float v2 = selu_f(acc[mi][ni][2] + bv[2]);
                    float v3 = selu_f(acc[mi][ni][3] + bv[3]);
                    u32x2 d = {pk2h(v0, v1), pk2h(v2, v3)};
                    *(u32x2*)&lds[row * 512 +
                        ((w * 128 + ni * 32 + lgrp * 8) ^ ((row & 7) << 4))] = d;
                }
            }
        } else {
            // ---- epilogue: 4 rounds of 16 rows (mi = cc) via 16KB B region ----
            float bc[4];
#pragma unroll
            for (int ni = 0; ni < 4; ++ni) bc[ni] = biasArr[2 * HF + w * 64 + ni * 16 + lrow];
            unsigned char* EP = lds + 32768;
#pragma unroll
            for (int cc = 0; cc < 4; ++cc) {
                if (cc) __syncthreads();
#pragma unroll
                for (int ni = 0; ni < 4; ++ni)
#pragma unroll
                    for (int r = 0; r < 4; ++r) {
                        int er = lgrp * 4 + r;             // row within round 0..15
                        int cg = w * 64 + ni * 16 + lrow;
                        float val = selu_f(acc[cc][ni][r] + bc[ni]);
                        *(float*)&EP[er * 1024 + ((cg * 4) ^ ((er & 7) << 4))] = val;
                        int e = base + cc * 16 + er;
                        atomicAdd(agg + (size_t)dstI[e] * HF + cg, val);
                    }
                __syncthreads();
#pragma unroll
                for (int i = 0; i < 4; ++i) {
                    int f = t + i * 256;                  // 1024 x 16B = 16 rows x 64
                    int row = f >> 6, ch = f & 63;
                    f32x4 v = *(const f32x4*)&EP[row * 1024 + ((ch * 16) ^ ((row & 7) << 4))];
                    *(f32x4*)(hB + (size_t)(base + cc * 16 + row) * 1024 + ch * 16) = v;
                }
            }
        }
    }
}

extern "C" void kernel_launch(void* const* d_in, const int* in_sizes, int n_in,
                              void* d_out, int out_size, void* d_ws, size_t ws_size,
                              hipStream_t stream) {
    const float* x     = (const float*)d_in[0];
    const int*   ei    = (const int*)d_in[1];
    const float* W0    = (const float*)d_in[2];
    const float* b0    = (const float*)d_in[3];
    const float* g0    = (const float*)d_in[4];
    const float* beta0 = (const float*)d_in[5];
    const float* m0    = (const float*)d_in[6];
    const float* v0    = (const float*)d_in[7];
    const float* Ws    = (const float*)d_in[8];
    const float* bs    = (const float*)d_in[9];
    const float* gs    = (const float*)d_in[10];
    const float* betas = (const float*)d_in[11];
    const float* ms    = (const float*)d_in[12];
    const float* vs    = (const float*)d_in[13];

    const int Nn = in_sizes[0] / IN_F;   // 20000
    const int E  = in_sizes[1] / 2;      // 320000

    float* agg  = (float*)d_out;
    float* hptr = agg + (size_t)Nn * HF;   // final h region of d_out

    // ws: Wf (384KB fp16, staged layout) | biasArr (3KB) | cnt (80KB)
    unsigned short* Wf = (unsigned short*)d_ws;
    float* biasArr = (float*)((char*)d_ws + 3 * HF * HF * sizeof(unsigned short));
    int* cnt = (int*)((char*)d_ws + 3 * HF * HF * sizeof(unsigned short) + 3 * HF * sizeof(float));

    const int* srcI = ei;        // edge_index[0]
    const int* dstI = ei + E;    // edge_index[1]

    prep_kernel<<<3 * HF, HF, 0, stream>>>(W0, b0, g0, beta0, m0, v0,
                                           Ws, bs, gs, betas, ms, vs, Wf, biasArr);
    hipMemsetAsync(cnt, 0, (size_t)Nn * sizeof(int), stream);
    hipMemsetAsync(agg, 0, (size_t)Nn * HF * sizeof(float), stream);
    count_kernel<<<(E + 255) / 256, 256, 0, stream>>>(dstI, cnt, E);

    fused_kernel<<<E / 64, 256, 0, stream>>>(x, dstI, srcI,
                                             (const unsigned char*)Wf, biasArr,
                                             (unsigned char*)hptr, agg);

    finalize_kernel<<<Nn, HF, 0, stream>>>(agg, cnt);
}

// Round 14
// 320.775 us; speedup vs baseline: 1.2556x; 1.2287x over previous
//
#include <hip/hip_runtime.h>
#include <hip/hip_bf16.h>

#define IN_F 128
#define HF 256
#define BN_EPS 1e-5f
#define SELU_SCALE 1.0507009873554805f
#define SELU_ALPHA 1.6732632423543772f

typedef __attribute__((ext_vector_type(8))) _Float16 half8;
typedef __attribute__((ext_vector_type(2))) unsigned int u32x2;
typedef __attribute__((ext_vector_type(4))) float f32x4;

__device__ __forceinline__ short f2h(float f) {
    _Float16 h = (_Float16)f;               // RTNE fp32->fp16
    return __builtin_bit_cast(short, h);
}

// fast SELU: native v_exp_f32
__device__ __forceinline__ float selu_f(float x) {
    const float SA = SELU_SCALE * SELU_ALPHA;
    float e = __expf(x);
    return x > 0.f ? SELU_SCALE * x : SA * e - SA;
}

// pack 2 fp32 -> 2 fp16 (RTZ), one instruction
__device__ __forceinline__ unsigned int pk2h(float a, float b) {
    return __builtin_bit_cast(unsigned int, __builtin_amdgcn_cvt_pkrtz(a, b));
}

// async global->LDS, 16B/lane; LDS dest MUST be wave-uniform (lane*16 implicit)
__device__ __forceinline__ void gld_lds16(const void* g, void* l) {
    __builtin_amdgcn_global_load_lds(
        (const __attribute__((address_space(1))) unsigned int*)g,
        (__attribute__((address_space(3))) unsigned int*)l, 16, 0, 0);
}

// Fold BN into weights. Layout = fused kernel's per-step (BK=32) B staging:
// Wf[layer][kk(8)][kc(4)][n(256)][j(8)] fp16, k = kk*32 + kc*8 + j.
__global__ void prep_kernel(const float* __restrict__ W0, const float* __restrict__ b0,
                            const float* __restrict__ g0, const float* __restrict__ beta0,
                            const float* __restrict__ m0, const float* __restrict__ v0,
                            const float* __restrict__ Ws, const float* __restrict__ bs,
                            const float* __restrict__ gs, const float* __restrict__ betas,
                            const float* __restrict__ ms, const float* __restrict__ vs,
                            unsigned short* __restrict__ Wf, float* __restrict__ biasArr) {
    int b = blockIdx.x;
    int layer = b >> 8;
    int n = b & 255;
    int k = threadIdx.x;
    const float *W, *bb, *g, *be, *m, *v;
    if (layer == 0) { W = W0; bb = b0; g = g0; be = beta0; m = m0; v = v0; }
    else {
        int i = layer - 1;
        W = Ws + (size_t)i * HF * HF; bb = bs + i * HF; g = gs + i * HF;
        be = betas + i * HF; m = ms + i * HF; v = vs + i * HF;
    }
    float s = g[n] * rsqrtf(v[n] + BN_EPS);
    int kk = k >> 5, kc = (k >> 3) & 3, j = k & 7;
    Wf[((((size_t)layer * 8 + kk) * 4 + kc) * 256 + n) * 8 + j] =
        (unsigned short)f2h(W[n * HF + k] * s);
    if (k == 0) biasArr[layer * HF + n] = (bb[n] - m[n]) * s + be[n];
}

__global__ void count_kernel(const int* __restrict__ dstI, int* __restrict__ cnt, int E) {
    int i = blockIdx.x * 256 + threadIdx.x;
    if (i < E) atomicAdd(cnt + dstI[i], 1);
}

// single-block exclusive scan of cnt[n] -> wrk[n] (running offsets for scatter)
__global__ void scan_kernel(const int* __restrict__ cnt, int* __restrict__ wrk, int n) {
    __shared__ int s[1024];
    __shared__ int carryS;
    int t = threadIdx.x;
    if (t == 0) carryS = 0;
    __syncthreads();
    for (int c0 = 0; c0 < n; c0 += 1024) {
        int i = c0 + t;
        int v = (i < n) ? cnt[i] : 0;
        s[t] = v;
        __syncthreads();
#pragma unroll
        for (int d = 1; d < 1024; d <<= 1) {
            int add = (t >= d) ? s[t - d] : 0;
            __syncthreads();
            s[t] += add;
            __syncthreads();
        }
        int incl = s[t];
        int base = carryS;
        if (i < n) wrk[i] = base + incl - v;
        __syncthreads();
        if (t == 1023) carryS = base + s[1023];
        __syncthreads();
    }
}

// perm[pos] = original edge id, grouped by dst (counting sort)
__global__ void scatter_kernel(const int* __restrict__ dstI, int* __restrict__ wrk,
                               int* __restrict__ perm, int E) {
    int i = blockIdx.x * 256 + threadIdx.x;
    if (i < E) {
        int p = atomicAdd(wrk + dstI[i], 1);
        perm[p] = i;
    }
}

__global__ void finalize_kernel(float* __restrict__ agg, const int* __restrict__ cnt) {
    int n = blockIdx.x;
    float c = fmaxf((float)cnt[n], 1.f);
    agg[(size_t)n * HF + threadIdx.x] = agg[(size_t)n * HF + threadIdx.x] / c;
}

// Fused 3-layer edge MLP over DST-SORTED edges. Block = 64 sorted edges x all
// 256 cols; 256 thr = 4 waves; wave = 64 rows x its 64-col slab.
// LDS 48KB -> 3 blocks/CU. A_act 32KB @0 (swizzled, resident across layers);
// B single 16KB @32768 (BK=32). K-step: {barrier; frag reads; barrier;
// stageB(next) under 16 MFMA}. Layers 1-2 swapped operands -> pkrtz handoff.
// Epilogue: per 16-row round, stage vals in LDS; h stored to ORIGINAL edge
// slot (perm); agg accumulated by per-column SEGMENT SUM over the sorted dst
// runs -> ~1 coalesced atomic per (dst,col) run instead of per edge (13x fewer).
__global__ __launch_bounds__(256, 3)
void fused_kernel(const float* __restrict__ x,
                  const int* __restrict__ dstI, const int* __restrict__ srcI,
                  const int* __restrict__ perm,
                  const unsigned char* __restrict__ Wfb,
                  const float* __restrict__ biasArr,
                  unsigned char* __restrict__ hB, float* __restrict__ agg) {
    __shared__ __align__(16) unsigned char lds[49152];
    __shared__ int peL[64];   // original edge id per sorted row
    __shared__ int pdL[64];   // dst per sorted row

    const int base = blockIdx.x * 64;
    const int t = threadIdx.x;
    const int lane = t & 63;
    const int w = t >> 6;           // 0..3 : 64-col slab
    const int lrow = lane & 15;
    const int lgrp = lane >> 4;

    // stage B(L,kk): 16KB, 4 wave-uniform gld_lds rounds
    auto stageB = [&](int L, int kk) {
        const unsigned char* src = Wfb + ((size_t)(L * 8 + kk) << 14);
        unsigned char* dstBase = lds + 32768 + w * 1024;
#pragma unroll
        for (int i = 0; i < 4; ++i)
            gld_lds16(src + (i * 256 + t) * 16, dstBase + i * 4096);
    };

    stageB(0, 0);   // prologue stage overlaps the gather below

    // ---- layer-1 A fill: gather x via perm (sorted: dst shared within block) ----
    {
        int r = t >> 2, q = t & 3;                 // sorted row, col-quarter
        int e = perm[base + r];
        int idx = (q < 2 ? dstI : srcI)[e];
        const float* xr = x + (size_t)idx * IN_F + (q & 1) * 64;
        int swz = (r & 7) << 4;
#pragma unroll
        for (int u = 0; u < 16; ++u) {
            f32x4 v = *(const f32x4*)(xr + u * 4);
            u32x2 hv = {pk2h(v[0], v[1]), pk2h(v[2], v[3])};
            *(u32x2*)&lds[r * 512 + ((q * 128 + u * 8) ^ swz)] = hv;
        }
    }

    f32x4 acc[4][4];
    const f32x4 zero = {0.f, 0.f, 0.f, 0.f};

#pragma unroll
    for (int L = 0; L < 3; ++L) {
#pragma unroll
        for (int mi = 0; mi < 4; ++mi)
#pragma unroll
            for (int ni = 0; ni < 4; ++ni) acc[mi][ni] = zero;

#pragma unroll
        for (int kk = 0; kk < 8; ++kk) {
            __syncthreads();   // B(kk) staged; A_act (gather/handoff) visible

            half8 af[4], bf[4];
#pragma unroll
            for (int mi = 0; mi < 4; ++mi) {
                int row = mi * 16 + lrow;
                af[mi] = *(const half8*)&lds[row * 512 +
                    ((kk * 64 + lgrp * 16) ^ ((row & 7) << 4))];
            }
#pragma unroll
            for (int ni = 0; ni < 4; ++ni)
                bf[ni] = *(const half8*)&lds[32768 + lgrp * 4096 +
                                             (w * 64 + ni * 16 + lrow) * 16];
            __syncthreads();   // all reads done -> B buffer free

            if (kk < 7) stageB(L, kk + 1);
            else if (L < 2) stageB(L + 1, 0);

            if (L < 2) {
#pragma unroll
                for (int mi = 0; mi < 4; ++mi)
#pragma unroll
                    for (int ni = 0; ni < 4; ++ni)
                        acc[mi][ni] = __builtin_amdgcn_mfma_f32_16x16x32_f16(
                            bf[ni], af[mi], acc[mi][ni], 0, 0, 0);
            } else {
#pragma unroll
                for (int mi = 0; mi < 4; ++mi)
#pragma unroll
                    for (int ni = 0; ni < 4; ++ni)
                        acc[mi][ni] = __builtin_amdgcn_mfma_f32_16x16x32_f16(
                            af[mi], bf[ni], acc[mi][ni], 0, 0, 0);
            }
        }

        if (L < 2) {
            // ---- handoff (swapped layout): lane&15=edge, reg-dim=col ----
#pragma unroll
            for (int ni = 0; ni < 4; ++ni) {
                f32x4 bv = *(const f32x4*)(biasArr + L * HF + w * 64 + ni * 16 + lgrp * 4);
#pragma unroll
                for (int mi = 0; mi < 4; ++mi) {
                    int row = mi * 16 + lrow;
                    float v0 = selu_f(acc[mi][ni][0] + bv[0]);
                    float v1 = selu_f(acc[mi][ni][1] + bv[1]);
                    float v2 = selu_f(acc[mi][ni][2] + bv[2]);
                    float v3 = selu_f(acc[mi][ni][3] + bv[3]);
                    u32x2 d = {pk2h(v0, v1), pk2h(v2, v3)};
                    *(u32x2*)&lds[row * 512 +
                        ((w * 128 + ni * 32 + lgrp * 8) ^ ((row & 7) << 4))] = d;
                }
            }
        } else {
            // ---- epilogue: 4 rounds of 16 rows (mi = cc) via 16KB B region ----
            if (t < 64) {                     // sorted-row metadata for this block
                int e = perm[base + t];
                peL[t] = e;
                pdL[t] = dstI[e];
            }
            float bc[4];
#pragma unroll
            for (int ni = 0; ni < 4; ++ni) bc[ni] = biasArr[2 * HF + w * 64 + ni * 16 + lrow];
            unsigned char* EP = lds + 32768;
            int curD = -1;
            float carry = 0.f;                // per-column (t) running segment sum
#pragma unroll
            for (int cc = 0; cc < 4; ++cc) {
                if (cc) __syncthreads();
#pragma unroll
                for (int ni = 0; ni < 4; ++ni)
#pragma unroll
                    for (int r = 0; r < 4; ++r) {
                        int er = lgrp * 4 + r;             // row within round 0..15
                        int cg = w * 64 + ni * 16 + lrow;
                        float val = selu_f(acc[cc][ni][r] + bc[ni]);
                        *(float*)&EP[er * 1024 + ((cg * 4) ^ ((er & 7) << 4))] = val;
                    }
                __syncthreads();              // EP + peL/pdL visible
                // h rows -> original edge slots
#pragma unroll
                for (int i = 0; i < 4; ++i) {
                    int f = t + i * 256;                  // 1024 x 16B = 16 rows x 64
                    int row = f >> 6, ch = f & 63;
                    f32x4 v = *(const f32x4*)&EP[row * 1024 + ((ch * 16) ^ ((row & 7) << 4))];
                    *(f32x4*)(hB + (size_t)peL[cc * 16 + row] * 1024 + ch * 16) = v;
                }
                // segment sum: thread t = column t, walk the 16 sorted rows
#pragma unroll
                for (int r = 0; r < 16; ++r) {
                    float v = *(const float*)&EP[r * 1024 + ((t * 4) ^ ((r & 7) << 4))];
                    int d = pdL[cc * 16 + r];
                    if (d != curD) {
                        if (curD >= 0) atomicAdd(agg + (size_t)curD * HF + t, carry);
                        carry = 0.f;
                        curD = d;
                    }
                    carry += v;
                }
            }
            atomicAdd(agg + (size_t)curD * HF + t, carry);   // flush last segment
        }
    }
}

extern "C" void kernel_launch(void* const* d_in, const int* in_sizes, int n_in,
                              void* d_out, int out_size, void* d_ws, size_t ws_size,
                              hipStream_t stream) {
    const float* x     = (const float*)d_in[0];
    const int*   ei    = (const int*)d_in[1];
    const float* W0    = (const float*)d_in[2];
    const float* b0    = (const float*)d_in[3];
    const float* g0    = (const float*)d_in[4];
    const float* beta0 = (const float*)d_in[5];
    const float* m0    = (const float*)d_in[6];
    const float* v0    = (const float*)d_in[7];
    const float* Ws    = (const float*)d_in[8];
    const float* bs    = (const float*)d_in[9];
    const float* gs    = (const float*)d_in[10];
    const float* betas = (const float*)d_in[11];
    const float* ms    = (const float*)d_in[12];
    const float* vs    = (const float*)d_in[13];

    const int Nn = in_sizes[0] / IN_F;   // 20000
    const int E  = in_sizes[1] / 2;      // 320000

    float* agg  = (float*)d_out;
    float* hptr = agg + (size_t)Nn * HF;   // final h region of d_out

    // ws layout (byte offsets): Wf 384KB | bias 3KB | cnt 80KB | wrk 80KB | perm 1.25MB
    char* wsb = (char*)d_ws;
    unsigned short* Wf = (unsigned short*)wsb;                      // 393216 B
    float* biasArr = (float*)(wsb + 393216);                        // 3072 B
    int* cnt  = (int*)(wsb + 396288);                               // 80000 B
    int* wrk  = (int*)(wsb + 476288);                               // 80000 B
    int* perm = (int*)(wsb + 556288);                               // 1280000 B

    const int* srcI = ei;        // edge_index[0]
    const int* dstI = ei + E;    // edge_index[1]

    prep_kernel<<<3 * HF, HF, 0, stream>>>(W0, b0, g0, beta0, m0, v0,
                                           Ws, bs, gs, betas, ms, vs, Wf, biasArr);
    hipMemsetAsync(cnt, 0, (size_t)Nn * sizeof(int), stream);
    hipMemsetAsync(agg, 0, (size_t)Nn * HF * sizeof(float), stream);
    count_kernel<<<(E + 255) / 256, 256, 0, stream>>>(dstI, cnt, E);
    scan_kernel<<<1, 1024, 0, stream>>>(cnt, wrk, Nn);
    scatter_kernel<<<(E + 255) / 256, 256, 0, stream>>>(dstI, wrk, perm, E);

    fused_kernel<<<E / 64, 256, 0, stream>>>(x, dstI, srcI, perm,
                                             (const unsigned char*)Wf, biasArr,
                                             (unsigned char*)hptr, agg);

    finalize_kernel<<<Nn, HF, 0, stream>>>(agg, cnt);
}

// Round 15
// 316.899 us; speedup vs baseline: 1.2710x; 1.0122x over previous
//
#include <hip/hip_runtime.h>
#include <hip/hip_bf16.h>

#define IN_F 128
#define HF 256
#define BN_EPS 1e-5f
#define SELU_SCALE 1.0507009873554805f
#define SELU_ALPHA 1.6732632423543772f

typedef __attribute__((ext_vector_type(8))) _Float16 half8;
typedef __attribute__((ext_vector_type(2))) unsigned int u32x2;
typedef __attribute__((ext_vector_type(4))) float f32x4;

__device__ __forceinline__ short f2h(float f) {
    _Float16 h = (_Float16)f;               // RTNE fp32->fp16
    return __builtin_bit_cast(short, h);
}

// fast SELU: native v_exp_f32
__device__ __forceinline__ float selu_f(float x) {
    const float SA = SELU_SCALE * SELU_ALPHA;
    float e = __expf(x);
    return x > 0.f ? SELU_SCALE * x : SA * e - SA;
}

// pack 2 fp32 -> 2 fp16 (RTZ), one instruction
__device__ __forceinline__ unsigned int pk2h(float a, float b) {
    return __builtin_bit_cast(unsigned int, __builtin_amdgcn_cvt_pkrtz(a, b));
}

// async global->LDS, 16B/lane; LDS dest MUST be wave-uniform (lane*16 implicit)
__device__ __forceinline__ void gld_lds16(const void* g, void* l) {
    __builtin_amdgcn_global_load_lds(
        (const __attribute__((address_space(1))) unsigned int*)g,
        (__attribute__((address_space(3))) unsigned int*)l, 16, 0, 0);
}

// Fold BN into weights. Layout = fused kernel's per-step (BK=32) B staging:
// Wf[layer][kk(8)][kc(4)][n(256)][j(8)] fp16, k = kk*32 + kc*8 + j.
__global__ void prep_kernel(const float* __restrict__ W0, const float* __restrict__ b0,
                            const float* __restrict__ g0, const float* __restrict__ beta0,
                            const float* __restrict__ m0, const float* __restrict__ v0,
                            const float* __restrict__ Ws, const float* __restrict__ bs,
                            const float* __restrict__ gs, const float* __restrict__ betas,
                            const float* __restrict__ ms, const float* __restrict__ vs,
                            unsigned short* __restrict__ Wf, float* __restrict__ biasArr) {
    int b = blockIdx.x;
    int layer = b >> 8;
    int n = b & 255;
    int k = threadIdx.x;
    const float *W, *bb, *g, *be, *m, *v;
    if (layer == 0) { W = W0; bb = b0; g = g0; be = beta0; m = m0; v = v0; }
    else {
        int i = layer - 1;
        W = Ws + (size_t)i * HF * HF; bb = bs + i * HF; g = gs + i * HF;
        be = betas + i * HF; m = ms + i * HF; v = vs + i * HF;
    }
    float s = g[n] * rsqrtf(v[n] + BN_EPS);
    int kk = k >> 5, kc = (k >> 3) & 3, j = k & 7;
    Wf[((((size_t)layer * 8 + kk) * 4 + kc) * 256 + n) * 8 + j] =
        (unsigned short)f2h(W[n * HF + k] * s);
    if (k == 0) biasArr[layer * HF + n] = (bb[n] - m[n]) * s + be[n];
}

__global__ void count_kernel(const int* __restrict__ dstI, int* __restrict__ cnt, int E) {
    int i = blockIdx.x * 256 + threadIdx.x;
    if (i < E) atomicAdd(cnt + dstI[i], 1);
}

// 3-phase parallel exclusive scan of cnt -> wrk
__global__ void scan_local(const int* __restrict__ cnt, int* __restrict__ wrk,
                           int* __restrict__ btot, int n) {
    __shared__ int s[1024];
    int b = blockIdx.x, t = threadIdx.x, i = b * 1024 + t;
    int v = (i < n) ? cnt[i] : 0;
    s[t] = v;
    __syncthreads();
#pragma unroll
    for (int d = 1; d < 1024; d <<= 1) {
        int add = (t >= d) ? s[t - d] : 0;
        __syncthreads();
        s[t] += add;
        __syncthreads();
    }
    if (i < n) wrk[i] = s[t] - v;
    if (t == 1023) btot[b] = s[1023];
}
__global__ void scan_tops(int* __restrict__ btot, int nb) {
    if (threadIdx.x == 0) {
        int run = 0;
        for (int i = 0; i < nb; ++i) { int v = btot[i]; btot[i] = run; run += v; }
    }
}
__global__ void scan_add(int* __restrict__ wrk, const int* __restrict__ btot, int n) {
    int i = blockIdx.x * 1024 + threadIdx.x;
    if (i < n) wrk[i] += btot[blockIdx.x];
}

// perm[pos] = original edge id, grouped by dst (counting sort)
__global__ void scatter_kernel(const int* __restrict__ dstI, int* __restrict__ wrk,
                               int* __restrict__ perm, int E) {
    int i = blockIdx.x * 256 + threadIdx.x;
    if (i < E) {
        int p = atomicAdd(wrk + dstI[i], 1);
        perm[p] = i;
    }
}

__global__ void finalize_kernel(float* __restrict__ agg, const int* __restrict__ cnt) {
    int n = blockIdx.x;
    float c = fmaxf((float)cnt[n], 1.f);
    agg[(size_t)n * HF + threadIdx.x] = agg[(size_t)n * HF + threadIdx.x] / c;
}

// Fused 3-layer edge MLP over DST-SORTED edges. Block = 64 sorted edges x all
// 256 cols; 256 thr = 4 waves; wave = 64 rows x its 64-col slab.
// LDS 48KB -> 3 blocks/CU. A_act 32KB @0 (swizzled, resident across layers);
// B single 16KB @32768 (BK=32). ALL layers use swapped mfma operands
// (lane&15=edge, reg-dim=col). Layer-3 output: h stored DIRECTLY from regs
// (per edge: 4 waves x 256B contiguous = full 1KB row at its original slot);
// agg via segment-sum over sorted dst runs in 2 rounds of 32 rows through the
// dead A_act region (EP), ~1 coalesced atomic per (dst,col) run.
__global__ __launch_bounds__(256, 3)
void fused_kernel(const float* __restrict__ x,
                  const int* __restrict__ dstI, const int* __restrict__ srcI,
                  const int* __restrict__ perm,
                  const unsigned char* __restrict__ Wfb,
                  const float* __restrict__ biasArr,
                  unsigned char* __restrict__ hB, float* __restrict__ agg) {
    __shared__ __align__(16) unsigned char lds[49152];
    __shared__ int peL[64];   // original edge id per sorted row
    __shared__ int pdL[64];   // dst per sorted row

    const int base = blockIdx.x * 64;
    const int t = threadIdx.x;
    const int lane = t & 63;
    const int w = t >> 6;           // 0..3 : 64-col slab
    const int lrow = lane & 15;
    const int lgrp = lane >> 4;

    // stage B(L,kk): 16KB, 4 wave-uniform gld_lds rounds
    auto stageB = [&](int L, int kk) {
        const unsigned char* src = Wfb + ((size_t)(L * 8 + kk) << 14);
        unsigned char* dstBase = lds + 32768 + w * 1024;
#pragma unroll
        for (int i = 0; i < 4; ++i)
            gld_lds16(src + (i * 256 + t) * 16, dstBase + i * 4096);
    };

    stageB(0, 0);   // prologue stage overlaps the gather below

    // ---- layer-1 A fill: gather x via perm (sorted: dst shared within block) ----
    {
        int r = t >> 2, q = t & 3;                 // sorted row, col-quarter
        int e = perm[base + r];
        int idx = (q < 2 ? dstI : srcI)[e];
        const float* xr = x + (size_t)idx * IN_F + (q & 1) * 64;
        int swz = (r & 7) << 4;
#pragma unroll
        for (int u = 0; u < 16; ++u) {
            f32x4 v = *(const f32x4*)(xr + u * 4);
            u32x2 hv = {pk2h(v[0], v[1]), pk2h(v[2], v[3])};
            *(u32x2*)&lds[r * 512 + ((q * 128 + u * 8) ^ swz)] = hv;
        }
    }

    f32x4 acc[4][4];
    const f32x4 zero = {0.f, 0.f, 0.f, 0.f};

#pragma unroll
    for (int L = 0; L < 3; ++L) {
#pragma unroll
        for (int mi = 0; mi < 4; ++mi)
#pragma unroll
            for (int ni = 0; ni < 4; ++ni) acc[mi][ni] = zero;

#pragma unroll
        for (int kk = 0; kk < 8; ++kk) {
            __syncthreads();   // B(kk) staged; A_act (gather/handoff) visible

            half8 af[4], bf[4];
#pragma unroll
            for (int mi = 0; mi < 4; ++mi) {
                int row = mi * 16 + lrow;
                af[mi] = *(const half8*)&lds[row * 512 +
                    ((kk * 64 + lgrp * 16) ^ ((row & 7) << 4))];
            }
#pragma unroll
            for (int ni = 0; ni < 4; ++ni)
                bf[ni] = *(const half8*)&lds[32768 + lgrp * 4096 +
                                             (w * 64 + ni * 16 + lrow) * 16];
            __syncthreads();   // all reads done -> B buffer free

            if (kk < 7) stageB(L, kk + 1);
            else if (L < 2) stageB(L + 1, 0);

#pragma unroll
            for (int mi = 0; mi < 4; ++mi)
#pragma unroll
                for (int ni = 0; ni < 4; ++ni)
                    acc[mi][ni] = __builtin_amdgcn_mfma_f32_16x16x32_f16(
                        bf[ni], af[mi], acc[mi][ni], 0, 0, 0);
        }

        if (L < 2) {
            // ---- handoff (swapped layout): lane&15=edge, reg-dim=col ----
#pragma unroll
            for (int ni = 0; ni < 4; ++ni) {
                f32x4 bv = *(const f32x4*)(biasArr + L * HF + w * 64 + ni * 16 + lgrp * 4);
#pragma unroll
                for (int mi = 0; mi < 4; ++mi) {
                    int row = mi * 16 + lrow;
                    float v0 = selu_f(acc[mi][ni][0] + bv[0]);
                    float v1 = selu_f(acc[mi][ni][1] + bv[1]);
                    float v2 = selu_f(acc[mi][ni][2] + bv[2]);
                    float v3 = selu_f(acc[mi][ni][3] + bv[3]);
                    u32x2 d = {pk2h(v0, v1), pk2h(v2, v3)};
                    *(u32x2*)&lds[row * 512 +
                        ((w * 128 + ni * 32 + lgrp * 8) ^ ((row & 7) << 4))] = d;
                }
            }
        } else {
            // ---- layer-3 finish: bias+SELU in regs (swapped layout) ----
#pragma unroll
            for (int ni = 0; ni < 4; ++ni) {
                f32x4 bv = *(const f32x4*)(biasArr + 2 * HF + w * 64 + ni * 16 + lgrp * 4);
#pragma unroll
                for (int mi = 0; mi < 4; ++mi) {
#pragma unroll
                    for (int r = 0; r < 4; ++r)
                        acc[mi][ni][r] = selu_f(acc[mi][ni][r] + bv[r]);
                }
            }
            // sorted-row metadata (A_act reads done at last k-step's 2nd barrier)
            if (t < 64) {
                int e = perm[base + t];
                peL[t] = e;
                pdL[t] = dstI[e];
            }
            // EP = dead A_act region (32KB): 2 rounds of 32 rows (mi = 2p, 2p+1)
            int curD = -1;
            float carry = 0.f;                // per-column (t) running segment sum
#pragma unroll
            for (int p = 0; p < 2; ++p) {
                if (p) __syncthreads();       // prev walk done before EP rewrite
#pragma unroll
                for (int m2 = 0; m2 < 2; ++m2) {
                    int mi = p * 2 + m2;
#pragma unroll
                    for (int ni = 0; ni < 4; ++ni)
#pragma unroll
                        for (int r = 0; r < 4; ++r) {
                            int er = m2 * 16 + lrow;             // 0..31
                            int cg = w * 64 + ni * 16 + lgrp * 4 + r;
                            *(float*)&lds[er * 1024 + ((cg * 4) ^ ((er & 7) << 4))] =
                                acc[mi][ni][r];
                        }
                }
                __syncthreads();              // EP + metadata visible
                // h direct stores for this round's rows (overlaps the walk)
#pragma unroll
                for (int m2 = 0; m2 < 2; ++m2) {
                    int mi = p * 2 + m2;
                    size_t eoff = (size_t)peL[mi * 16 + lrow] << 10;
#pragma unroll
                    for (int ni = 0; ni < 4; ++ni)
                        *(f32x4*)(hB + eoff + (w * 64 + ni * 16 + lgrp * 4) * 4) =
                            acc[mi][ni];
                }
                // segment sum: thread t = column t, walk this round's 32 rows
#pragma unroll
                for (int r = 0; r < 32; ++r) {
                    float v = *(const float*)&lds[r * 1024 + ((t * 4) ^ ((r & 7) << 4))];
                    int d = pdL[p * 32 + r];
                    if (d != curD) {
                        if (curD >= 0) atomicAdd(agg + (size_t)curD * HF + t, carry);
                        carry = 0.f;
                        curD = d;
                    }
                    carry += v;
                }
            }
            atomicAdd(agg + (size_t)curD * HF + t, carry);   // flush last segment
        }
    }
}

extern "C" void kernel_launch(void* const* d_in, const int* in_sizes, int n_in,
                              void* d_out, int out_size, void* d_ws, size_t ws_size,
                              hipStream_t stream) {
    const float* x     = (const float*)d_in[0];
    const int*   ei    = (const int*)d_in[1];
    const float* W0    = (const float*)d_in[2];
    const float* b0    = (const float*)d_in[3];
    const float* g0    = (const float*)d_in[4];
    const float* beta0 = (const float*)d_in[5];
    const float* m0    = (const float*)d_in[6];
    const float* v0    = (const float*)d_in[7];
    const float* Ws    = (const float*)d_in[8];
    const float* bs    = (const float*)d_in[9];
    const float* gs    = (const float*)d_in[10];
    const float* betas = (const float*)d_in[11];
    const float* ms    = (const float*)d_in[12];
    const float* vs    = (const float*)d_in[13];

    const int Nn = in_sizes[0] / IN_F;   // 20000
    const int E  = in_sizes[1] / 2;      // 320000

    float* agg  = (float*)d_out;
    float* hptr = agg + (size_t)Nn * HF;   // final h region of d_out

    // ws layout (byte offsets): Wf 384KB | bias 3KB | cnt 80KB | wrk 80KB | perm 1.25MB
    char* wsb = (char*)d_ws;
    unsigned short* Wf = (unsigned short*)wsb;                      // 393216 B
    float* biasArr = (float*)(wsb + 393216);                        // 3072 B
    int* cnt  = (int*)(wsb + 396288);                               // 80000 B
    int* wrk  = (int*)(wsb + 476288);                               // 80000 B
    int* perm = (int*)(wsb + 556288);                               // 1280000 B
    int* btot = (int*)agg;            // scratch: agg region, re-zeroed below

    const int* srcI = ei;        // edge_index[0]
    const int* dstI = ei + E;    // edge_index[1]

    const int nScan = (Nn + 1023) / 1024;   // 20

    prep_kernel<<<3 * HF, HF, 0, stream>>>(W0, b0, g0, beta0, m0, v0,
                                           Ws, bs, gs, betas, ms, vs, Wf, biasArr);
    hipMemsetAsync(cnt, 0, (size_t)Nn * sizeof(int), stream);
    count_kernel<<<(E + 255) / 256, 256, 0, stream>>>(dstI, cnt, E);
    scan_local<<<nScan, 1024, 0, stream>>>(cnt, wrk, btot, Nn);
    scan_tops<<<1, 64, 0, stream>>>(btot, nScan);
    scan_add<<<nScan, 1024, 0, stream>>>(wrk, btot, Nn);
    hipMemsetAsync(agg, 0, (size_t)Nn * HF * sizeof(float), stream);  // clears btot too
    scatter_kernel<<<(E + 255) / 256, 256, 0, stream>>>(dstI, wrk, perm, E);

    fused_kernel<<<E / 64, 256, 0, stream>>>(x, dstI, srcI, perm,
                                             (const unsigned char*)Wf, biasArr,
                                             (unsigned char*)hptr, agg);

    finalize_kernel<<<Nn, HF, 0, stream>>>(agg, cnt);
}

// Round 16
// 291.676 us; speedup vs baseline: 1.3809x; 1.0865x over previous
//
#include <hip/hip_runtime.h>
#include <hip/hip_bf16.h>

#define IN_F 128
#define HF 256
#define BN_EPS 1e-5f
#define SELU_SCALE 1.0507009873554805f
#define SELU_ALPHA 1.6732632423543772f

typedef __attribute__((ext_vector_type(8))) _Float16 half8;
typedef __attribute__((ext_vector_type(2))) unsigned int u32x2;
typedef __attribute__((ext_vector_type(4))) float f32x4;

__device__ __forceinline__ short f2h(float f) {
    _Float16 h = (_Float16)f;               // RTNE fp32->fp16
    return __builtin_bit_cast(short, h);
}

// fast SELU: native v_exp_f32
__device__ __forceinline__ float selu_f(float x) {
    const float SA = SELU_SCALE * SELU_ALPHA;
    float e = __expf(x);
    return x > 0.f ? SELU_SCALE * x : SA * e - SA;
}

// pack 2 fp32 -> 2 fp16 (RTZ), one instruction
__device__ __forceinline__ unsigned int pk2h(float a, float b) {
    return __builtin_bit_cast(unsigned int, __builtin_amdgcn_cvt_pkrtz(a, b));
}

// async global->LDS, 16B/lane; LDS dest MUST be wave-uniform (lane*16 implicit)
__device__ __forceinline__ void gld_lds16(const void* g, void* l) {
    __builtin_amdgcn_global_load_lds(
        (const __attribute__((address_space(1))) unsigned int*)g,
        (__attribute__((address_space(3))) unsigned int*)l, 16, 0, 0);
}

// Fold BN into weights. Layout = fused kernel's per-step (BK=32) B staging:
// Wf[layer][kk(8)][kc(4)][n(256)][j(8)] fp16, k = kk*32 + kc*8 + j.
__global__ void prep_kernel(const float* __restrict__ W0, const float* __restrict__ b0,
                            const float* __restrict__ g0, const float* __restrict__ beta0,
                            const float* __restrict__ m0, const float* __restrict__ v0,
                            const float* __restrict__ Ws, const float* __restrict__ bs,
                            const float* __restrict__ gs, const float* __restrict__ betas,
                            const float* __restrict__ ms, const float* __restrict__ vs,
                            unsigned short* __restrict__ Wf, float* __restrict__ biasArr) {
    int b = blockIdx.x;
    int layer = b >> 8;
    int n = b & 255;
    int k = threadIdx.x;
    const float *W, *bb, *g, *be, *m, *v;
    if (layer == 0) { W = W0; bb = b0; g = g0; be = beta0; m = m0; v = v0; }
    else {
        int i = layer - 1;
        W = Ws + (size_t)i * HF * HF; bb = bs + i * HF; g = gs + i * HF;
        be = betas + i * HF; m = ms + i * HF; v = vs + i * HF;
    }
    float s = g[n] * rsqrtf(v[n] + BN_EPS);
    int kk = k >> 5, kc = (k >> 3) & 3, j = k & 7;
    Wf[((((size_t)layer * 8 + kk) * 4 + kc) * 256 + n) * 8 + j] =
        (unsigned short)f2h(W[n * HF + k] * s);
    if (k == 0) biasArr[layer * HF + n] = (bb[n] - m[n]) * s + be[n];
}

__global__ void count_kernel(const int* __restrict__ dstI, int* __restrict__ cnt, int E) {
    int i = blockIdx.x * 256 + threadIdx.x;
    if (i < E) atomicAdd(cnt + dstI[i], 1);
}

// 3-phase parallel exclusive scan of cnt -> wrk
__global__ void scan_local(const int* __restrict__ cnt, int* __restrict__ wrk,
                           int* __restrict__ btot, int n) {
    __shared__ int s[1024];
    int b = blockIdx.x, t = threadIdx.x, i = b * 1024 + t;
    int v = (i < n) ? cnt[i] : 0;
    s[t] = v;
    __syncthreads();
#pragma unroll
    for (int d = 1; d < 1024; d <<= 1) {
        int add = (t >= d) ? s[t - d] : 0;
        __syncthreads();
        s[t] += add;
        __syncthreads();
    }
    if (i < n) wrk[i] = s[t] - v;
    if (t == 1023) btot[b] = s[1023];
}
__global__ void scan_tops(int* __restrict__ btot, int nb) {
    if (threadIdx.x == 0) {
        int run = 0;
        for (int i = 0; i < nb; ++i) { int v = btot[i]; btot[i] = run; run += v; }
    }
}
__global__ void scan_add(int* __restrict__ wrk, const int* __restrict__ btot, int n) {
    int i = blockIdx.x * 1024 + threadIdx.x;
    if (i < n) wrk[i] += btot[blockIdx.x];
}

// perm[pos] = original edge id, grouped by dst (counting sort)
__global__ void scatter_kernel(const int* __restrict__ dstI, int* __restrict__ wrk,
                               int* __restrict__ perm, int E) {
    int i = blockIdx.x * 256 + threadIdx.x;
    if (i < E) {
        int p = atomicAdd(wrk + dstI[i], 1);
        perm[p] = i;
    }
}

__global__ void finalize_kernel(float* __restrict__ agg, const int* __restrict__ cnt) {
    int n = blockIdx.x;
    float c = fmaxf((float)cnt[n], 1.f);
    agg[(size_t)n * HF + threadIdx.x] = agg[(size_t)n * HF + threadIdx.x] / c;
}

// Fused 3-layer edge MLP over DST-SORTED edges. Block = 64 sorted edges x all
// 256 cols; 256 thr = 4 waves; wave = 64 rows x its 64-col slab.
// LDS 48KB -> 3 blocks/CU. A_act 32KB @0 (swizzled, resident across layers);
// B single 16KB @32768 (BK=32). K-step: {barrier; frag reads; barrier;
// stageB(next) under 16 MFMA}. Layers 1-2 swapped operands -> pkrtz handoff.
// Epilogue (measured-best R14 form): per 16-row round, stage vals in LDS;
// h stored to ORIGINAL edge slot (perm) as full 1KB rows; agg accumulated by
// per-column SEGMENT SUM over sorted dst runs -> ~1 atomic per (dst,col) run.
__global__ __launch_bounds__(256, 3)
void fused_kernel(const float* __restrict__ x,
                  const int* __restrict__ dstI, const int* __restrict__ srcI,
                  const int* __restrict__ perm,
                  const unsigned char* __restrict__ Wfb,
                  const float* __restrict__ biasArr,
                  unsigned char* __restrict__ hB, float* __restrict__ agg) {
    __shared__ __align__(16) unsigned char lds[49152];
    __shared__ int peL[64];   // original edge id per sorted row
    __shared__ int pdL[64];   // dst per sorted row

    const int base = blockIdx.x * 64;
    const int t = threadIdx.x;
    const int lane = t & 63;
    const int w = t >> 6;           // 0..3 : 64-col slab
    const int lrow = lane & 15;
    const int lgrp = lane >> 4;

    // stage B(L,kk): 16KB, 4 wave-uniform gld_lds rounds
    auto stageB = [&](int L, int kk) {
        const unsigned char* src = Wfb + ((size_t)(L * 8 + kk) << 14);
        unsigned char* dstBase = lds + 32768 + w * 1024;
#pragma unroll
        for (int i = 0; i < 4; ++i)
            gld_lds16(src + (i * 256 + t) * 16, dstBase + i * 4096);
    };

    stageB(0, 0);   // prologue stage overlaps the gather below

    // ---- layer-1 A fill: gather x via perm (sorted: dst shared within block) ----
    {
        int r = t >> 2, q = t & 3;                 // sorted row, col-quarter
        int e = perm[base + r];
        int idx = (q < 2 ? dstI : srcI)[e];
        const float* xr = x + (size_t)idx * IN_F + (q & 1) * 64;
        int swz = (r & 7) << 4;
#pragma unroll
        for (int u = 0; u < 16; ++u) {
            f32x4 v = *(const f32x4*)(xr + u * 4);
            u32x2 hv = {pk2h(v[0], v[1]), pk2h(v[2], v[3])};
            *(u32x2*)&lds[r * 512 + ((q * 128 + u * 8) ^ swz)] = hv;
        }
    }

    f32x4 acc[4][4];
    const f32x4 zero = {0.f, 0.f, 0.f, 0.f};

#pragma unroll
    for (int L = 0; L < 3; ++L) {
#pragma unroll
        for (int mi = 0; mi < 4; ++mi)
#pragma unroll
            for (int ni = 0; ni < 4; ++ni) acc[mi][ni] = zero;

#pragma unroll
        for (int kk = 0; kk < 8; ++kk) {
            __syncthreads();   // B(kk) staged; A_act (gather/handoff) visible

            half8 af[4], bf[4];
#pragma unroll
            for (int mi = 0; mi < 4; ++mi) {
                int row = mi * 16 + lrow;
                af[mi] = *(const half8*)&lds[row * 512 +
                    ((kk * 64 + lgrp * 16) ^ ((row & 7) << 4))];
            }
#pragma unroll
            for (int ni = 0; ni < 4; ++ni)
                bf[ni] = *(const half8*)&lds[32768 + lgrp * 4096 +
                                             (w * 64 + ni * 16 + lrow) * 16];
            __syncthreads();   // all reads done -> B buffer free

            if (kk < 7) stageB(L, kk + 1);
            else if (L < 2) stageB(L + 1, 0);

            if (L < 2) {
#pragma unroll
                for (int mi = 0; mi < 4; ++mi)
#pragma unroll
                    for (int ni = 0; ni < 4; ++ni)
                        acc[mi][ni] = __builtin_amdgcn_mfma_f32_16x16x32_f16(
                            bf[ni], af[mi], acc[mi][ni], 0, 0, 0);
            } else {
#pragma unroll
                for (int mi = 0; mi < 4; ++mi)
#pragma unroll
                    for (int ni = 0; ni < 4; ++ni)
                        acc[mi][ni] = __builtin_amdgcn_mfma_f32_16x16x32_f16(
                            af[mi], bf[ni], acc[mi][ni], 0, 0, 0);
            }
        }

        if (L < 2) {
            // ---- handoff (swapped layout): lane&15=edge, reg-dim=col ----
#pragma unroll
            for (int ni = 0; ni < 4; ++ni) {
                f32x4 bv = *(const f32x4*)(biasArr + L * HF + w * 64 + ni * 16 + lgrp * 4);
#pragma unroll
                for (int mi = 0; mi < 4; ++mi) {
                    int row = mi * 16 + lrow;
                    float v0 = selu_f(acc[mi][ni][0] + bv[0]);
                    float v1 = selu_f(acc[mi][ni][1] + bv[1]);
                    float v2 = selu_f(acc[mi][ni][2] + bv[2]);
                    float v3 = selu_f(acc[mi][ni][3] + bv[3]);
                    u32x2 d = {pk2h(v0, v1), pk2h(v2, v3)};
                    *(u32x2*)&lds[row * 512 +
                        ((w * 128 + ni * 32 + lgrp * 8) ^ ((row & 7) << 4))] = d;
                }
            }
        } else {
            // ---- epilogue: 4 rounds of 16 rows (mi = cc) via 16KB B region ----
            if (t < 64) {                     // sorted-row metadata for this block
                int e = perm[base + t];
                peL[t] = e;
                pdL[t] = dstI[e];
            }
            float bc[4];
#pragma unroll
            for (int ni = 0; ni < 4; ++ni) bc[ni] = biasArr[2 * HF + w * 64 + ni * 16 + lrow];
            unsigned char* EP = lds + 32768;
            int curD = -1;
            float carry = 0.f;                // per-column (t) running segment sum
#pragma unroll
            for (int cc = 0; cc < 4; ++cc) {
                if (cc) __syncthreads();
#pragma unroll
                for (int ni = 0; ni < 4; ++ni)
#pragma unroll
                    for (int r = 0; r < 4; ++r) {
                        int er = lgrp * 4 + r;             // row within round 0..15
                        int cg = w * 64 + ni * 16 + lrow;
                        float val = selu_f(acc[cc][ni][r] + bc[ni]);
                        *(float*)&EP[er * 1024 + ((cg * 4) ^ ((er & 7) << 4))] = val;
                    }
                __syncthreads();              // EP + peL/pdL visible
                // h rows -> original edge slots (full 1KB rows, coalesced)
#pragma unroll
                for (int i = 0; i < 4; ++i) {
                    int f = t + i * 256;                  // 1024 x 16B = 16 rows x 64
                    int row = f >> 6, ch = f & 63;
                    f32x4 v = *(const f32x4*)&EP[row * 1024 + ((ch * 16) ^ ((row & 7) << 4))];
                    *(f32x4*)(hB + (size_t)peL[cc * 16 + row] * 1024 + ch * 16) = v;
                }
                // segment sum: thread t = column t, walk the 16 sorted rows
#pragma unroll
                for (int r = 0; r < 16; ++r) {
                    float v = *(const float*)&EP[r * 1024 + ((t * 4) ^ ((r & 7) << 4))];
                    int d = pdL[cc * 16 + r];
                    if (d != curD) {
                        if (curD >= 0) atomicAdd(agg + (size_t)curD * HF + t, carry);
                        carry = 0.f;
                        curD = d;
                    }
                    carry += v;
                }
            }
            atomicAdd(agg + (size_t)curD * HF + t, carry);   // flush last segment
        }
    }
}

extern "C" void kernel_launch(void* const* d_in, const int* in_sizes, int n_in,
                              void* d_out, int out_size, void* d_ws, size_t ws_size,
                              hipStream_t stream) {
    const float* x     = (const float*)d_in[0];
    const int*   ei    = (const int*)d_in[1];
    const float* W0    = (const float*)d_in[2];
    const float* b0    = (const float*)d_in[3];
    const float* g0    = (const float*)d_in[4];
    const float* beta0 = (const float*)d_in[5];
    const float* m0    = (const float*)d_in[6];
    const float* v0    = (const float*)d_in[7];
    const float* Ws    = (const float*)d_in[8];
    const float* bs    = (const float*)d_in[9];
    const float* gs    = (const float*)d_in[10];
    const float* betas = (const float*)d_in[11];
    const float* ms    = (const float*)d_in[12];
    const float* vs    = (const float*)d_in[13];

    const int Nn = in_sizes[0] / IN_F;   // 20000
    const int E  = in_sizes[1] / 2;      // 320000

    float* agg  = (float*)d_out;
    float* hptr = agg + (size_t)Nn * HF;   // final h region of d_out

    // ws layout (byte offsets): Wf 384KB | bias 3KB | cnt 80KB | wrk 80KB | perm 1.25MB
    char* wsb = (char*)d_ws;
    unsigned short* Wf = (unsigned short*)wsb;                      // 393216 B
    float* biasArr = (float*)(wsb + 393216);                        // 3072 B
    int* cnt  = (int*)(wsb + 396288);                               // 80000 B
    int* wrk  = (int*)(wsb + 476288);                               // 80000 B
    int* perm = (int*)(wsb + 556288);                               // 1280000 B
    int* btot = (int*)agg;            // scratch: agg region, re-zeroed below

    const int* srcI = ei;        // edge_index[0]
    const int* dstI = ei + E;    // edge_index[1]

    const int nScan = (Nn + 1023) / 1024;   // 20

    prep_kernel<<<3 * HF, HF, 0, stream>>>(W0, b0, g0, beta0, m0, v0,
                                           Ws, bs, gs, betas, ms, vs, Wf, biasArr);
    hipMemsetAsync(cnt, 0, (size_t)Nn * sizeof(int), stream);
    count_kernel<<<(E + 255) / 256, 256, 0, stream>>>(dstI, cnt, E);
    scan_local<<<nScan, 1024, 0, stream>>>(cnt, wrk, btot, Nn);
    scan_tops<<<1, 64, 0, stream>>>(btot, nScan);
    scan_add<<<nScan, 1024, 0, stream>>>(wrk, btot, Nn);
    hipMemsetAsync(agg, 0, (size_t)Nn * HF * sizeof(float), stream);  // clears btot too
    scatter_kernel<<<(E + 255) / 256, 256, 0, stream>>>(dstI, wrk, perm, E);

    fused_kernel<<<E / 64, 256, 0, stream>>>(x, dstI, srcI, perm,
                                             (const unsigned char*)Wf, biasArr,
                                             (unsigned char*)hptr, agg);

    finalize_kernel<<<Nn, HF, 0, stream>>>(agg, cnt);
}